// Round 10
// baseline (139.776 us; speedup 1.0000x reference)
//
#include <hip/hip_runtime.h>
#include <hip/hip_fp16.h>
#include <cstdint>

typedef __attribute__((ext_vector_type(8))) _Float16 f16x8;
typedef __attribute__((ext_vector_type(4))) float f32x4;
typedef __attribute__((ext_vector_type(16))) float f32x16;

__device__ __forceinline__ f16x8 cvt8(float4 x, float4 y) {
    f16x8 r;
    r[0] = (_Float16)x.x; r[1] = (_Float16)x.y; r[2] = (_Float16)x.z; r[3] = (_Float16)x.w;
    r[4] = (_Float16)y.x; r[5] = (_Float16)y.y; r[6] = (_Float16)y.z; r[7] = (_Float16)y.w;
    return r;
}

__device__ __forceinline__ f16x8 relu8(f16x8 v) {
    f16x8 z = {};
    return __builtin_elementwise_max(v, z);   // v_pk_max_f16
}

// =============== xpose: W1 transpose->f16, W2ext pack, Gram, ||q||^2 ===============
// (verbatim round 7 — verified correct)
__global__ __launch_bounds__(256)
void xpose(const float* __restrict__ query,
           const float* __restrict__ prot,
           const float* __restrict__ W1,
           const float* __restrict__ W2,
           const float* __restrict__ b2,
           _Float16* __restrict__ w1t,
           f16x8* __restrict__ w2p,
           float* __restrict__ Gm,
           float* __restrict__ q2) {
    int b = blockIdx.x, t = threadIdx.x;
    if (b < 32) {
        __shared__ _Float16 lt[64][73];
        int bi = b >> 2, bj = b & 3;
        int r0 = bi * 64, c0 = bj * 64;
        #pragma unroll
        for (int it = 0; it < 4; ++it) {
            int row = it * 16 + (t >> 4);
            int c4 = (t & 15) * 4;
            float4 v = *(const float4*)(W1 + (r0 + row) * 256 + c0 + c4);
            lt[row][c4]     = (_Float16)v.x;
            lt[row][c4 + 1] = (_Float16)v.y;
            lt[row][c4 + 2] = (_Float16)v.z;
            lt[row][c4 + 3] = (_Float16)v.w;
        }
        __syncthreads();
        int c = t >> 2, kq = t & 3;
        unsigned short o[16];
        #pragma unroll
        for (int i = 0; i < 16; ++i) {
            union { _Float16 f; unsigned short s; } u;
            u.f = lt[kq * 16 + i][c];
            o[i] = u.s;
        }
        _Float16* dst = w1t + (r0 >= 256 ? 65536 : 0) + (c0 + c) * 256 + (r0 & 255) + kq * 16;
        *(uint4*)dst       = *(uint4*)&o[0];
        *(uint4*)(dst + 8) = *(uint4*)&o[8];
    } else if (b < 49) {
        int chunk = (b - 32) * 256 + t;          // 0..4351
        int ks = chunk >> 8, h = (chunk >> 7) & 1, c = chunk & 127;
        f16x8 o = {};
        if (ks < 16) {
            #pragma unroll
            for (int j = 0; j < 8; ++j)
                o[j] = (_Float16)W2[(ks * 16 + h * 8 + j) * 128 + c];
        } else if (h == 0) {
            o[0] = (_Float16)b2[c];
        }
        w2p[chunk] = o;
    } else if (b < 81) {
        int pid = (b - 49) * 32 + (t >> 3), l8 = t & 7;
        int c = pid >> 6, k = (pid >> 3) & 7, kp = pid & 7;
        const float4* pa = (const float4*)(prot + (c * 8 + k) * 256 + l8 * 32);
        const float4* pb = (const float4*)(prot + (c * 8 + kp) * 256 + l8 * 32);
        float s = 0.f;
        #pragma unroll
        for (int i = 0; i < 8; ++i) {
            float4 x = pa[i], y = pb[i];
            s += x.x * y.x + x.y * y.y + x.z * y.z + x.w * y.w;
        }
        s += __shfl_xor(s, 1); s += __shfl_xor(s, 2); s += __shfl_xor(s, 4);
        if (l8 == 0) Gm[pid] = s;
    } else {
        int m = (b - 81) * 32 + (t >> 3), l8 = t & 7;
        const float4* qp = (const float4*)(query + m * 256 + l8 * 32);
        float s = 0.f;
        #pragma unroll
        for (int i = 0; i < 8; ++i) {
            float4 x = qp[i];
            s += x.x * x.x + x.y * x.y + x.z * x.z + x.w * x.w;
        }
        s += __shfl_xor(s, 1); s += __shfl_xor(s, 2); s += __shfl_xor(s, 4);
        if (l8 == 0) q2[m] = s;
    }
}

// =============== prepg: MFMA GEMMs, 64x64 tiles, 200 blocks ===============
// (verbatim round 7 — verified correct)
__global__ __launch_bounds__(256, 2)
void prepg(const float* __restrict__ query,
           const float* __restrict__ prot,
           const _Float16* __restrict__ w1t,
           const float* __restrict__ b1,
           _Float16* __restrict__ qh16,
           float* __restrict__ sqp,
           _Float16* __restrict__ phpk) {
    int b = blockIdx.x, t = threadIdx.x;
    int w = t >> 6, l = t & 63, l15 = l & 15, l4 = l >> 4;
    int mode, row0, col0;
    if (b < 128)      { mode = 0; row0 = (b >> 2) * 64;         col0 = (b & 3) * 64; }
    else if (b < 192) { mode = 1; row0 = ((b - 128) >> 1) * 64; col0 = ((b - 128) & 1) * 64; }
    else              { mode = 2; row0 = ((b - 192) >> 2) * 64; col0 = ((b - 192) & 3) * 64; }
    const float* Asrc = (mode == 2) ? prot : query;
    const _Float16* Bsrc = (mode == 2) ? (w1t + 65536) : w1t;

    f32x4 acc[4];
    #pragma unroll
    for (int nt = 0; nt < 4; ++nt) acc[nt] = (f32x4){0.f, 0.f, 0.f, 0.f};

    for (int ks = 0; ks < 8; ++ks) {
        int row = row0 + w * 16 + l15;
        const float* ap = Asrc + row * 256 + ks * 32 + l4 * 8;
        f16x8 af = cvt8(*(const float4*)ap, *(const float4*)(ap + 4));
        f16x8 bf[4];
        #pragma unroll
        for (int nt = 0; nt < 4; ++nt) {
            int col = col0 + nt * 16 + l15;
            if (mode == 1) {
                const float* bp = prot + col * 256 + ks * 32 + l4 * 8;
                bf[nt] = cvt8(*(const float4*)bp, *(const float4*)(bp + 4));
            } else {
                bf[nt] = *(const f16x8*)(Bsrc + col * 256 + ks * 32 + l4 * 8);
            }
        }
        #pragma unroll
        for (int nt = 0; nt < 4; ++nt)
            acc[nt] = __builtin_amdgcn_mfma_f32_16x16x32_f16(af, bf[nt], acc[nt], 0, 0, 0);
    }
    #pragma unroll
    for (int nt = 0; nt < 4; ++nt)
        #pragma unroll
        for (int j = 0; j < 4; ++j) {
            int row = row0 + w * 16 + l4 * 4 + j;
            int col = col0 + nt * 16 + l15;
            float v = acc[nt][j];
            if (mode == 0)      qh16[row * 256 + col] = (_Float16)v;
            else if (mode == 1) sqp[row * 128 + col] = v;
            else                phpk[(((col >> 4) * 2 + ((col >> 3) & 1)) * 128 + row) * 8
                                     + (col & 7)] = (_Float16)(v + b1[col]);
        }
}

// =============== fused2: 4-wave blocks, 2 blocks/CU, barrier-free m-loop ===============
// 256 thr = 4 waves; wave rg owns 32 ck rows x ALL 128 H2 cols (acc[4] f32x16) for one m.
// Scores wave-local -> no __syncthreads, no spart. grid = 512 blocks (2/CU), 4 m/block.
__global__ __launch_bounds__(256, 2)
void fused2(const _Float16* __restrict__ qh16,
            const _Float16* __restrict__ phpk,
            const uint4* __restrict__ w2p,
            const float* __restrict__ sqp,
            const float* __restrict__ q2,
            const float* __restrict__ Gm,
            const float* __restrict__ W3,
            float* __restrict__ out) {
    __shared__ uint4 w2l[4352];               // W2ext: [ks 17][h 2][col 128] x 16B = 68 KB
    __shared__ float w3l[128];

    int t = threadIdx.x;
    int rg = t >> 6, l = t & 63;
    int lk = l & 31, h = l >> 5;
    int ck = rg * 32 + lk;
    int c = rg * 4 + (lk >> 3), kk = l & 7;

    #pragma unroll
    for (int i = 0; i < 17; ++i) w2l[t + i * 256] = w2p[t + i * 256];
    if (t < 128) w3l[t] = W3[t];

    // php fragments: m-invariant, registers (64 VGPR)
    f16x8 ph[16];
    #pragma unroll
    for (int ks = 0; ks < 16; ++ks)
        ph[ks] = *(const f16x8*)(phpk + ((ks * 2 + h) * 128 + ck) * 8);

    __syncthreads();

    const _Float16* w2lh = (const _Float16*)w2l;
    int m0 = blockIdx.x * 4;

    for (int mi = 0; mi < 4; ++mi) {
        int m = m0 + mi;
        const _Float16* qrow = qh16 + m * 256 + h * 8;

        f32x16 acc[4];
        #pragma unroll
        for (int ct = 0; ct < 4; ++ct) acc[ct] = (f32x16){};

        f16x8 qv[4];
        #pragma unroll
        for (int p = 0; p < 4; ++p) qv[p] = *(const f16x8*)(qrow + p * 16);

        #pragma unroll
        for (int ks = 0; ks < 16; ++ks) {
            f16x8 act = relu8(qv[ks & 3] + ph[ks]);
            if (ks < 12) qv[ks & 3] = *(const f16x8*)(qrow + (ks + 4) * 16);
            #pragma unroll
            for (int ct = 0; ct < 4; ++ct) {
                f16x8 bfr = *(const f16x8*)(w2lh + ((ks * 2 + h) * 128 + ct * 32 + lk) * 8);
                acc[ct] = __builtin_amdgcn_mfma_f32_32x32x16_f16(bfr, act, acc[ct], 0, 0, 0);
            }
        }
        {   // K-extension step: adds b2 (A'ext = b2, B'ext = 1)
            f16x8 e = {};
            if (h == 0) e[0] = (_Float16)1.0f;
            #pragma unroll
            for (int ct = 0; ct < 4; ++ct) {
                f16x8 bfr = *(const f16x8*)(w2lh + ((32 + h) * 128 + ct * 32 + lk) * 8);
                acc[ct] = __builtin_amdgcn_mfma_f32_32x32x16_f16(bfr, e, acc[ct], 0, 0, 0);
            }
        }

        // score for prototype ck: in-lane over this half's 64 cols + 1 shfl for the rest
        float s = 0.f;
        #pragma unroll
        for (int ct = 0; ct < 4; ++ct)
            #pragma unroll
            for (int r = 0; r < 16; ++r)
                s = fmaf(fmaxf(acc[ct][r], 0.f),
                         w3l[ct * 32 + (r & 3) + 8 * (r >> 2) + 4 * h], s);
        s += __shfl_xor(s, 32);

        // softmax over K=8 within the 8-lane group
        float mx = s;
        mx = fmaxf(mx, __shfl_xor(mx, 1));
        mx = fmaxf(mx, __shfl_xor(mx, 2));
        mx = fmaxf(mx, __shfl_xor(mx, 4));
        float e2 = __expf(s - mx);
        float den = e2;
        den += __shfl_xor(den, 1); den += __shfl_xor(den, 2); den += __shfl_xor(den, 4);
        float a = e2 / den;

        // distance via Gram expansion
        float p2 = a * sqp[m * 128 + ck];
        float p3 = 0.f;
        #pragma unroll
        for (int kq = 0; kq < 8; ++kq) {
            float ak = __shfl(a, (l & 56) | kq);
            p3 = fmaf(ak, Gm[c * 64 + kq * 8 + kk], p3);
        }
        p3 *= a;
        float pr = p3 - 2.f * p2;
        pr += __shfl_xor(pr, 1); pr += __shfl_xor(pr, 2); pr += __shfl_xor(pr, 4);
        if (l < 32 && kk == 0)
            out[m * 16 + c] = -sqrtf(fmaxf(q2[m] + pr, 0.f));
    }
}

extern "C" void kernel_launch(void* const* d_in, const int* in_sizes, int n_in,
                              void* d_out, int out_size, void* d_ws, size_t ws_size,
                              hipStream_t stream) {
    const float* query = (const float*)d_in[0];
    const float* prot  = (const float*)d_in[1];
    const float* W1    = (const float*)d_in[2];
    const float* b1    = (const float*)d_in[3];
    const float* W2    = (const float*)d_in[4];
    const float* b2    = (const float*)d_in[5];
    const float* W3    = (const float*)d_in[6];
    // b3 (d_in[7]): constant pre-softmax shift -> softmax-invariant: unused.

    char* ws = (char*)d_ws;
    _Float16* qh16 = (_Float16*)(ws);                 // 2048*256*2 = 1048576
    _Float16* w1t  = (_Float16*)(ws + 1048576);       // 512*256*2  = 262144
    f16x8*    w2p  = (f16x8*)(ws + 1310720);          // 4352*16    = 69632
    _Float16* phpk = (_Float16*)(ws + 1380352);       // 128*256*2  = 65536
    float*    sqp  = (float*)(ws + 1445888);          // 2048*128*4 = 1048576
    float*    q2   = (float*)(ws + 2494464);          // 2048*4     = 8192
    float*    Gm   = (float*)(ws + 2502656);          // 1024*4     = 4096
    float* out = (float*)d_out;

    xpose<<<145, 256, 0, stream>>>(query, prot, W1, W2, b2, w1t, w2p, Gm, q2);
    prepg<<<200, 256, 0, stream>>>(query, prot, w1t, b1, qh16, sqp, phpk);
    fused2<<<512, 256, 0, stream>>>(qh16, phpk, (const uint4*)w2p,
                                    sqp, q2, Gm, W3, out);
}

// Round 12
// 46.154 us; speedup vs baseline: 3.0284x; 3.0284x over previous
//
#include <hip/hip_runtime.h>
#include <hip/hip_fp16.h>
#include <cstdint>

typedef __attribute__((ext_vector_type(8))) _Float16 f16x8;
typedef __attribute__((ext_vector_type(4))) float f32x4;
typedef __attribute__((ext_vector_type(16))) float f32x16;

__device__ __forceinline__ f16x8 cvt8(float4 x, float4 y) {
    f16x8 r;
    r[0] = (_Float16)x.x; r[1] = (_Float16)x.y; r[2] = (_Float16)x.z; r[3] = (_Float16)x.w;
    r[4] = (_Float16)y.x; r[5] = (_Float16)y.y; r[6] = (_Float16)y.z; r[7] = (_Float16)y.w;
    return r;
}

__device__ __forceinline__ f16x8 relu8(f16x8 v) {
    f16x8 z = {};
    return __builtin_elementwise_max(v, z);   // v_pk_max_f16
}

// =============== xpose: W1 transpose->f16, W2ext pack, Gram, ||q||^2 ===============
// (verbatim round 7 — verified correct)
__global__ __launch_bounds__(256)
void xpose(const float* __restrict__ query,
           const float* __restrict__ prot,
           const float* __restrict__ W1,
           const float* __restrict__ W2,
           const float* __restrict__ b2,
           _Float16* __restrict__ w1t,
           f16x8* __restrict__ w2p,
           float* __restrict__ Gm,
           float* __restrict__ q2) {
    int b = blockIdx.x, t = threadIdx.x;
    if (b < 32) {
        __shared__ _Float16 lt[64][73];
        int bi = b >> 2, bj = b & 3;
        int r0 = bi * 64, c0 = bj * 64;
        #pragma unroll
        for (int it = 0; it < 4; ++it) {
            int row = it * 16 + (t >> 4);
            int c4 = (t & 15) * 4;
            float4 v = *(const float4*)(W1 + (r0 + row) * 256 + c0 + c4);
            lt[row][c4]     = (_Float16)v.x;
            lt[row][c4 + 1] = (_Float16)v.y;
            lt[row][c4 + 2] = (_Float16)v.z;
            lt[row][c4 + 3] = (_Float16)v.w;
        }
        __syncthreads();
        int c = t >> 2, kq = t & 3;
        unsigned short o[16];
        #pragma unroll
        for (int i = 0; i < 16; ++i) {
            union { _Float16 f; unsigned short s; } u;
            u.f = lt[kq * 16 + i][c];
            o[i] = u.s;
        }
        _Float16* dst = w1t + (r0 >= 256 ? 65536 : 0) + (c0 + c) * 256 + (r0 & 255) + kq * 16;
        *(uint4*)dst       = *(uint4*)&o[0];
        *(uint4*)(dst + 8) = *(uint4*)&o[8];
    } else if (b < 49) {
        int chunk = (b - 32) * 256 + t;          // 0..4351
        int ks = chunk >> 8, h = (chunk >> 7) & 1, c = chunk & 127;
        f16x8 o = {};
        if (ks < 16) {
            #pragma unroll
            for (int j = 0; j < 8; ++j)
                o[j] = (_Float16)W2[(ks * 16 + h * 8 + j) * 128 + c];
        } else if (h == 0) {
            o[0] = (_Float16)b2[c];
        }
        w2p[chunk] = o;
    } else if (b < 81) {
        int pid = (b - 49) * 32 + (t >> 3), l8 = t & 7;
        int c = pid >> 6, k = (pid >> 3) & 7, kp = pid & 7;
        const float4* pa = (const float4*)(prot + (c * 8 + k) * 256 + l8 * 32);
        const float4* pb = (const float4*)(prot + (c * 8 + kp) * 256 + l8 * 32);
        float s = 0.f;
        #pragma unroll
        for (int i = 0; i < 8; ++i) {
            float4 x = pa[i], y = pb[i];
            s += x.x * y.x + x.y * y.y + x.z * y.z + x.w * y.w;
        }
        s += __shfl_xor(s, 1); s += __shfl_xor(s, 2); s += __shfl_xor(s, 4);
        if (l8 == 0) Gm[pid] = s;
    } else {
        int m = (b - 81) * 32 + (t >> 3), l8 = t & 7;
        const float4* qp = (const float4*)(query + m * 256 + l8 * 32);
        float s = 0.f;
        #pragma unroll
        for (int i = 0; i < 8; ++i) {
            float4 x = qp[i];
            s += x.x * x.x + x.y * x.y + x.z * x.z + x.w * x.w;
        }
        s += __shfl_xor(s, 1); s += __shfl_xor(s, 2); s += __shfl_xor(s, 4);
        if (l8 == 0) q2[m] = s;
    }
}

// =============== prepg: MFMA GEMMs, 64x64 tiles, 200 blocks ===============
// (verbatim round 7 — verified correct)
__global__ __launch_bounds__(256, 2)
void prepg(const float* __restrict__ query,
           const float* __restrict__ prot,
           const _Float16* __restrict__ w1t,
           const float* __restrict__ b1,
           _Float16* __restrict__ qh16,
           float* __restrict__ sqp,
           _Float16* __restrict__ phpk) {
    int b = blockIdx.x, t = threadIdx.x;
    int w = t >> 6, l = t & 63, l15 = l & 15, l4 = l >> 4;
    int mode, row0, col0;
    if (b < 128)      { mode = 0; row0 = (b >> 2) * 64;         col0 = (b & 3) * 64; }
    else if (b < 192) { mode = 1; row0 = ((b - 128) >> 1) * 64; col0 = ((b - 128) & 1) * 64; }
    else              { mode = 2; row0 = ((b - 192) >> 2) * 64; col0 = ((b - 192) & 3) * 64; }
    const float* Asrc = (mode == 2) ? prot : query;
    const _Float16* Bsrc = (mode == 2) ? (w1t + 65536) : w1t;

    f32x4 acc[4];
    #pragma unroll
    for (int nt = 0; nt < 4; ++nt) acc[nt] = (f32x4){0.f, 0.f, 0.f, 0.f};

    for (int ks = 0; ks < 8; ++ks) {
        int row = row0 + w * 16 + l15;
        const float* ap = Asrc + row * 256 + ks * 32 + l4 * 8;
        f16x8 af = cvt8(*(const float4*)ap, *(const float4*)(ap + 4));
        f16x8 bf[4];
        #pragma unroll
        for (int nt = 0; nt < 4; ++nt) {
            int col = col0 + nt * 16 + l15;
            if (mode == 1) {
                const float* bp = prot + col * 256 + ks * 32 + l4 * 8;
                bf[nt] = cvt8(*(const float4*)bp, *(const float4*)(bp + 4));
            } else {
                bf[nt] = *(const f16x8*)(Bsrc + col * 256 + ks * 32 + l4 * 8);
            }
        }
        #pragma unroll
        for (int nt = 0; nt < 4; ++nt)
            acc[nt] = __builtin_amdgcn_mfma_f32_16x16x32_f16(af, bf[nt], acc[nt], 0, 0, 0);
    }
    #pragma unroll
    for (int nt = 0; nt < 4; ++nt)
        #pragma unroll
        for (int j = 0; j < 4; ++j) {
            int row = row0 + w * 16 + l4 * 4 + j;
            int col = col0 + nt * 16 + l15;
            float v = acc[nt][j];
            if (mode == 0)      qh16[row * 256 + col] = (_Float16)v;
            else if (mode == 1) sqp[row * 128 + col] = v;
            else                phpk[(((col >> 4) * 2 + ((col >> 3) & 1)) * 128 + row) * 8
                                     + (col & 7)] = (_Float16)(v + b1[col]);
        }
}

// =============== fused2: round-7 math, 4-wave blocks, ck-split, 2 blocks/CU ===============
// 256 thr = 4 waves = 2 rg (32-ck strips) x 2 cs (64-col halves).
// Block owns 64 prototypes (ch = blockIdx&1) x 8 m (mg = blockIdx>>1); m-paired B-reuse.
// __launch_bounds__(256,1): avoids the empirical 128-reg cap (rounds 6/10 spill lesson).
// grid = 512 blocks = 2 independent blocks/CU -> cross-block latency hiding.
__global__ __launch_bounds__(256, 1)
void fused2(const _Float16* __restrict__ qh16,
            const _Float16* __restrict__ phpk,
            const uint4* __restrict__ w2p,
            const float* __restrict__ sqp,
            const float* __restrict__ q2,
            const float* __restrict__ Gm,
            const float* __restrict__ W3,
            float* __restrict__ out) {
    __shared__ uint4 w2l[4352];               // W2ext: [ks 17][h 2][col 128] x 16B = 68 KB
    __shared__ float w3l[128];
    __shared__ float spart[2][2][2][64];      // [buf][m-sel][cs][ck_local] = 2 KB

    int t = threadIdx.x;
    int wid = t >> 6, l = t & 63;
    int rg = wid & 1, cs = wid >> 1;
    int lk = l & 31, h = l >> 5;
    int ch = blockIdx.x & 1;                  // prototype half
    int mg = blockIdx.x >> 1;                 // m-group
    int ckl = rg * 32 + lk;                   // 0..63 local prototype row
    int ck = ch * 64 + ckl;                   // global prototype row

    for (int i = t; i < 4352; i += 256) w2l[i] = w2p[i];
    if (t < 128) w3l[t] = W3[t];

    // php fragments: m-invariant, registers (64 VGPR)
    f16x8 ph[16];
    #pragma unroll
    for (int ks = 0; ks < 16; ++ks)
        ph[ks] = *(const f16x8*)(phpk + ((ks * 2 + h) * 128 + ck) * 8);

    __syncthreads();

    const _Float16* w2lh = (const _Float16*)w2l;
    int m0 = mg * 8;

    for (int mi = 0; mi < 4; ++mi) {
        int mA = m0 + mi * 2;
        const _Float16* qra = qh16 + mA * 256 + h * 8;
        const _Float16* qrb = qra + 256;

        f32x16 acc[2][2];                     // [m][ct]
        #pragma unroll
        for (int mm = 0; mm < 2; ++mm)
            #pragma unroll
            for (int ct = 0; ct < 2; ++ct) acc[mm][ct] = (f32x16){};

        f16x8 qa[4], qb[4];
        #pragma unroll
        for (int p = 0; p < 4; ++p) {
            qa[p] = *(const f16x8*)(qra + p * 16);
            qb[p] = *(const f16x8*)(qrb + p * 16);
        }

        #pragma unroll
        for (int ks = 0; ks < 16; ++ks) {
            f16x8 aA = relu8(qa[ks & 3] + ph[ks]);
            f16x8 aB = relu8(qb[ks & 3] + ph[ks]);
            if (ks < 12) {                    // rolling 4-deep q prefetch
                qa[ks & 3] = *(const f16x8*)(qra + (ks + 4) * 16);
                qb[ks & 3] = *(const f16x8*)(qrb + (ks + 4) * 16);
            }
            #pragma unroll
            for (int ct = 0; ct < 2; ++ct) {
                f16x8 bfr = *(const f16x8*)(w2lh + ((ks * 2 + h) * 128 + cs * 64 + ct * 32 + lk) * 8);
                acc[0][ct] = __builtin_amdgcn_mfma_f32_32x32x16_f16(bfr, aA, acc[0][ct], 0, 0, 0);
                acc[1][ct] = __builtin_amdgcn_mfma_f32_32x32x16_f16(bfr, aB, acc[1][ct], 0, 0, 0);
            }
        }
        {   // K-extension step: adds b2 (A'ext = b2, B'ext = 1)
            f16x8 e = {};
            if (h == 0) e[0] = (_Float16)1.0f;
            #pragma unroll
            for (int ct = 0; ct < 2; ++ct) {
                f16x8 bfr = *(const f16x8*)(w2lh + ((32 + h) * 128 + cs * 64 + ct * 32 + lk) * 8);
                acc[0][ct] = __builtin_amdgcn_mfma_f32_32x32x16_f16(bfr, e, acc[0][ct], 0, 0, 0);
                acc[1][ct] = __builtin_amdgcn_mfma_f32_32x32x16_f16(bfr, e, acc[1][ct], 0, 0, 0);
            }
        }

        // partial score over this wave's 64 cols (both h-halves via xor32)
        int buf = mi & 1;
        #pragma unroll
        for (int mm = 0; mm < 2; ++mm) {
            float s = 0.f;
            #pragma unroll
            for (int ct = 0; ct < 2; ++ct)
                #pragma unroll
                for (int r = 0; r < 16; ++r)
                    s = fmaf(fmaxf(acc[mm][ct][r], 0.f),
                             w3l[cs * 64 + ct * 32 + (r & 3) + 8 * (r >> 2) + 4 * h], s);
            s += __shfl_xor(s, 32);
            if (l < 32) spart[buf][mm][cs][ckl] = s;
        }
        __syncthreads();

        // softmax over K=8 per c + Gram-expanded distance; t<128 covers 2m x 64 ck
        if (t < 128) {
            int msel = t >> 6, cl = t & 63, kk = t & 7;
            int m = mA + msel;
            int cg = ch * 8 + (cl >> 3);
            float s = spart[buf][msel][0][cl] + spart[buf][msel][1][cl];
            float mx = s;
            mx = fmaxf(mx, __shfl_xor(mx, 1));
            mx = fmaxf(mx, __shfl_xor(mx, 2));
            mx = fmaxf(mx, __shfl_xor(mx, 4));
            float e = __expf(s - mx);
            float den = e;
            den += __shfl_xor(den, 1); den += __shfl_xor(den, 2); den += __shfl_xor(den, 4);
            float a = e / den;
            float p2 = a * sqp[m * 128 + ch * 64 + cl];
            float p3 = 0.f;
            #pragma unroll
            for (int kq = 0; kq < 8; ++kq) {
                float ak = __shfl(a, (l & 56) | kq);
                p3 = fmaf(ak, Gm[cg * 64 + kq * 8 + kk], p3);
            }
            p3 *= a;
            float pr = p3 - 2.f * p2;
            pr += __shfl_xor(pr, 1); pr += __shfl_xor(pr, 2); pr += __shfl_xor(pr, 4);
            if (kk == 0)
                out[m * 16 + cg] = -sqrtf(fmaxf(q2[m] + pr, 0.f));
        }
    }
}

extern "C" void kernel_launch(void* const* d_in, const int* in_sizes, int n_in,
                              void* d_out, int out_size, void* d_ws, size_t ws_size,
                              hipStream_t stream) {
    const float* query = (const float*)d_in[0];
    const float* prot  = (const float*)d_in[1];
    const float* W1    = (const float*)d_in[2];
    const float* b1    = (const float*)d_in[3];
    const float* W2    = (const float*)d_in[4];
    const float* b2    = (const float*)d_in[5];
    const float* W3    = (const float*)d_in[6];
    // b3 (d_in[7]): constant pre-softmax shift -> softmax-invariant: unused.

    char* ws = (char*)d_ws;
    _Float16* qh16 = (_Float16*)(ws);                 // 2048*256*2 = 1048576
    _Float16* w1t  = (_Float16*)(ws + 1048576);       // 512*256*2  = 262144
    f16x8*    w2p  = (f16x8*)(ws + 1310720);          // 4352*16    = 69632
    _Float16* phpk = (_Float16*)(ws + 1380352);       // 128*256*2  = 65536
    float*    sqp  = (float*)(ws + 1445888);          // 2048*128*4 = 1048576
    float*    q2   = (float*)(ws + 2494464);          // 2048*4     = 8192
    float*    Gm   = (float*)(ws + 2502656);          // 1024*4     = 4096
    float* out = (float*)d_out;

    xpose<<<145, 256, 0, stream>>>(query, prot, W1, W2, b2, w1t, w2p, Gm, q2);
    prepg<<<200, 256, 0, stream>>>(query, prot, w1t, b1, qh16, sqp, phpk);
    fused2<<<512, 256, 0, stream>>>(qh16, phpk, (const uint4*)w2p,
                                    sqp, q2, Gm, W3, out);
}